// Round 6
// baseline (171.707 us; speedup 1.0000x reference)
//
#include <hip/hip_runtime.h>
#include <hip/hip_bf16.h>

#define DIM 256
#define NP 2048
#define NH 8
#define BATCH 2
#define DH 32

typedef __attribute__((ext_vector_type(8))) short bshort8;
typedef __attribute__((ext_vector_type(4))) short bshort4;
typedef __attribute__((ext_vector_type(4))) float f32x4;

#define LOG2E 1.44269504f
// (Dh^-0.5) * log2(e), folded into WT rows 0..255 (W_q) at prep time
#define QSCALE (0.17677669529663687f * LOG2E)

union U16B { uint4 u; bshort8 s8; __hip_bfloat16 h[8]; };
union U8B  { uint2 u; bshort4 s4; __hip_bfloat16 h[4]; };

__device__ __forceinline__ float fexp2(float x) { return __builtin_amdgcn_exp2f(x); }
// pack two fp32 -> two bf16 (truncation) in one v_perm
__device__ __forceinline__ unsigned packbf(float hi, float lo) {
    return __builtin_amdgcn_perm(__float_as_uint(hi), __float_as_uint(lo), 0x07060302u);
}

// ============ kernel 0: prep — W transpose->bf16 WT[1024][256], x->bf16 =====
// WT rows: 0-255 = Wq^T * QSCALE, 256-511 = Wk^T, 512-767 = Wv^T, 768-1023 = Wproj^T
__global__ __launch_bounds__(256) void prep_kernel(
    const float* __restrict__ x,
    const float* __restrict__ Wqk,
    const float* __restrict__ Wv,
    const float* __restrict__ Wproj,
    __hip_bfloat16* __restrict__ WT,
    __hip_bfloat16* __restrict__ xb) {
    const int t = threadIdx.x;
    const int blk = blockIdx.x;
    if (blk < 64) {
        __shared__ float ts[64][65];
        const int ct = blk >> 2, k0 = (blk & 3) * 64;
        const int c0 = ct * 64;
        const float* src; int ldw, cs0; float scl = 1.0f;
        if (ct < 8)       { src = Wqk;   ldw = 512; cs0 = c0;      if (ct < 4) scl = QSCALE; }
        else if (ct < 12) { src = Wv;    ldw = 256; cs0 = c0 - 512; }
        else              { src = Wproj; ldw = 256; cs0 = c0 - 768; }
        const int cc = t & 63, tq = t >> 6;
#pragma unroll
        for (int j = 0; j < 16; j++) {
            int kk = tq * 16 + j;
            ts[kk][cc] = src[(size_t)(k0 + kk) * ldw + cs0 + cc];
        }
        __syncthreads();
        const int kk2 = t & 63;
#pragma unroll
        for (int j = 0; j < 16; j++) {
            int cc2 = tq * 16 + j;
            WT[(size_t)(c0 + cc2) * 256 + k0 + kk2] = __float2bfloat16(ts[kk2][cc2] * scl);
        }
    } else {
        const size_t i0 = (size_t)(blk - 64) * 2048 + (size_t)t * 8;
        float4 f0 = *(const float4*)(x + i0);
        float4 f1 = *(const float4*)(x + i0 + 4);
        U16B o;
        o.h[0] = __float2bfloat16(f0.x); o.h[1] = __float2bfloat16(f0.y);
        o.h[2] = __float2bfloat16(f0.z); o.h[3] = __float2bfloat16(f0.w);
        o.h[4] = __float2bfloat16(f1.x); o.h[5] = __float2bfloat16(f1.y);
        o.h[6] = __float2bfloat16(f1.z); o.h[7] = __float2bfloat16(f1.w);
        *(uint4*)(xb + i0) = o.u;
    }
}

// ============ kernel 1: QKV projection, pure bf16 MFMA GEMM =================
// A = xb [4096x256], B = WT rows 0..767. grid (64,12), 256 thr.
__global__ __launch_bounds__(256) void qkv_mfma(
    const __hip_bfloat16* __restrict__ xb,
    const __hip_bfloat16* __restrict__ WT,
    __hip_bfloat16* __restrict__ q,
    __hip_bfloat16* __restrict__ k,
    __hip_bfloat16* __restrict__ vT) {
    const int t = threadIdx.x, lane = t & 63, wvid = t >> 6;
    const int l15 = lane & 15, l4 = lane >> 4;
    const int m0 = blockIdx.x * 64;
    const int nbase = blockIdx.y * 64 + wvid * 16;
    const int nc = nbase + l15;

    f32x4 acc[4] = {{0.f,0.f,0.f,0.f},{0.f,0.f,0.f,0.f},{0.f,0.f,0.f,0.f},{0.f,0.f,0.f,0.f}};
    const __hip_bfloat16* brow = WT + (size_t)nc * 256 + l4 * 8;
    const __hip_bfloat16* arow = xb + (size_t)(m0 + l15) * 256 + l4 * 8;

#pragma unroll
    for (int k0 = 0; k0 < 256; k0 += 32) {
        U16B bw; bw.u = *(const uint4*)(brow + k0);
#pragma unroll
        for (int mt = 0; mt < 4; mt++) {
            U16B ax; ax.u = *(const uint4*)(arow + (size_t)mt * 16 * 256 + k0);
            acc[mt] = __builtin_amdgcn_mfma_f32_16x16x32_bf16(ax.s8, bw.s8, acc[mt], 0, 0, 0);
        }
    }

    if (nbase < 256) {           // q (QSCALE already folded into WT)
        const int h = nc >> 5, d = nc & 31;
#pragma unroll
        for (int mt = 0; mt < 4; mt++)
#pragma unroll
            for (int r = 0; r < 4; r++) {
                int tok = m0 + mt * 16 + l4 * 4 + r;
                int b = tok >> 11, n = tok & (NP - 1);
                q[((size_t)(b * NH + h) * NP + n) * DH + d] = __float2bfloat16(acc[mt][r]);
            }
    } else if (nbase < 512) {    // k
        const int c = nc - 256, h = c >> 5, d = c & 31;
#pragma unroll
        for (int mt = 0; mt < 4; mt++)
#pragma unroll
            for (int r = 0; r < 4; r++) {
                int tok = m0 + mt * 16 + l4 * 4 + r;
                int b = tok >> 11, n = tok & (NP - 1);
                k[((size_t)(b * NH + h) * NP + n) * DH + d] = __float2bfloat16(acc[mt][r]);
            }
    } else {                     // vT[(b*256+c)][token], 8B stores
        const int c = nc - 512;
        const int b = m0 >> 11;
#pragma unroll
        for (int mt = 0; mt < 4; mt++) {
            int tokn = (m0 & (NP - 1)) + mt * 16 + l4 * 4;
            U8B vv;
#pragma unroll
            for (int r = 0; r < 4; r++) vv.h[r] = __float2bfloat16(acc[mt][r]);
            *(uint2*)(vT + (size_t)(b * 256 + c) * NP + tokn) = vv.u;
        }
    }
}

// ============ kernel 2: attention — register-only P path, in-block split-K ==
// grid 512 = (b,h) x 32 q-blocks of 64; 8 waves: qt = wv&3 (16 q), kh = wv>>2
// (key half). S^T frag (4 keys/lane) IS the 16x16x16 B-frag -> no LDS in loop.
__global__ __launch_bounds__(512, 4) void attn_kernel(
    const __hip_bfloat16* __restrict__ qg,
    const __hip_bfloat16* __restrict__ kg,
    const __hip_bfloat16* __restrict__ vTg,
    const float* __restrict__ Wpos,
    const float* __restrict__ bpos,
    const float* __restrict__ gating,
    __hip_bfloat16* __restrict__ ao) {
    __shared__ float cmb[4][2][32][16];   // [qt][type][d][q] upper-half partial O
    __shared__ float cls[4][2][16];       // [qt][type][q]    upper-half partial sums

    const int t = threadIdx.x;
    const int lane = t & 63, wvid = t >> 6;
    const int l15 = lane & 15, l4 = lane >> 4;
    const int qt = wvid & 3, kh = wvid >> 2;
    const int bh = blockIdx.x >> 5, qb = blockIdx.x & 31;
    const int h = bh & (NH - 1), b = bh >> 3;
    const int q0 = qb * 64 + qt * 16;
    const int myq = q0 + l15;

    const float w0 = Wpos[h] * LOG2E;
    const float w1 = Wpos[NH + h] * LOG2E;
    const float g = 1.0f / (1.0f + __expf(-gating[h]));
    const float nf = (float)myq;
    // analytic positional max over full key range (bias cancels in softmax)
    const float pmax = fmaxf(0.f, fmaxf((w0 + w1) * nf, (w1 - w0) * (2047.0f - nf)));
    const float npmax = -pmax;
    const float rA = fexp2(-(w0 + w1));   // step d -> d-1 while d >= 1
    const float rB = fexp2(w1 - w0);      // step d -> d-1 while d <= 0

    // Q as B-frag of 16x16x32: B[k=dh=l4*8+j][n=query=l15]
    U16B qv;
    qv.u = *(const uint4*)(qg + ((size_t)bh * NP + myq) * DH + l4 * 8);

    const __hip_bfloat16* kbase = kg + (size_t)bh * NP * DH;
    const __hip_bfloat16* vtb   = vTg + (size_t)bh * DH * NP;
    const int kstart = kh * 1024;

    f32x4 os0 = {0.f,0.f,0.f,0.f}, os1 = {0.f,0.f,0.f,0.f};
    f32x4 op0 = {0.f,0.f,0.f,0.f}, op1 = {0.f,0.f,0.f,0.f};
    float ls = 0.f, lp = 0.f;

    U16B kf[2][4];
    U8B  vf[2][8];  // [c*2 + dhalf]: A-frag of 16x16x16, 4 keys per lane
#pragma unroll
    for (int kt = 0; kt < 4; kt++)
        kf[0][kt].u = *(const uint4*)(kbase + (size_t)(kstart + kt * 16 + l15) * DH + l4 * 8);
#pragma unroll
    for (int c = 0; c < 4; c++) {
        vf[0][c * 2 + 0].u = *(const uint2*)(vtb + (size_t)l15 * NP + kstart + c * 16 + l4 * 4);
        vf[0][c * 2 + 1].u = *(const uint2*)(vtb + (size_t)(16 + l15) * NP + kstart + c * 16 + l4 * 4);
    }

#pragma unroll 2
    for (int it = 0; it < 16; ++it) {
        const int cur = it & 1, nxt = cur ^ 1;
        const int k0 = kstart + it * 64;

        // S^T = K@Q^T: D[key=l4*4+r][query=l15]
        f32x4 st[4];
#pragma unroll
        for (int kt = 0; kt < 4; kt++)
            st[kt] = __builtin_amdgcn_mfma_f32_16x16x32_bf16(
                kf[cur][kt].s8, qv.s8, (f32x4){0.f,0.f,0.f,0.f}, 0, 0, 0);

        // prefetch next iteration (wraps to kstart on last iter; values unused)
        const int kn0 = kstart + ((it < 15) ? (it + 1) * 64 : 0);
#pragma unroll
        for (int kt = 0; kt < 4; kt++)
            kf[nxt][kt].u = *(const uint4*)(kbase + (size_t)(kn0 + kt * 16 + l15) * DH + l4 * 8);
#pragma unroll
        for (int c = 0; c < 4; c++) {
            vf[nxt][c * 2 + 0].u = *(const uint2*)(vtb + (size_t)l15 * NP + kn0 + c * 16 + l4 * 4);
            vf[nxt][c * 2 + 1].u = *(const uint2*)(vtb + (size_t)(16 + l15) * NP + kn0 + c * 16 + l4 * 4);
        }

        // exp -> pack in registers -> AV MFMAs (16x16x16, K=16 per chunk)
#pragma unroll
        for (int kt = 0; kt < 4; kt++) {
            float es0 = fexp2(st[kt][0]), es1 = fexp2(st[kt][1]);
            float es2 = fexp2(st[kt][2]), es3 = fexp2(st[kt][3]);
            ls += (es0 + es1) + (es2 + es3);
            const float d0 = nf - (float)(k0 + kt * 16 + l4 * 4);
            float ep0 = fexp2(fmaf(w1, fabsf(d0), fmaf(w0, d0, npmax)));
            float ep1 = ep0 * ((d0 >= 1.f) ? rA : rB);
            float ep2 = ep1 * ((d0 >= 2.f) ? rA : rB);
            float ep3 = ep2 * ((d0 >= 3.f) ? rA : rB);
            lp += (ep0 + ep1) + (ep2 + ep3);
            U8B pc, pp;
            pc.u.x = packbf(es1, es0); pc.u.y = packbf(es3, es2);
            pp.u.x = packbf(ep1, ep0); pp.u.y = packbf(ep3, ep2);
            os0 = __builtin_amdgcn_mfma_f32_16x16x16bf16_1k(vf[cur][kt*2+0].s4, pc.s4, os0, 0, 0, 0);
            os1 = __builtin_amdgcn_mfma_f32_16x16x16bf16_1k(vf[cur][kt*2+1].s4, pc.s4, os1, 0, 0, 0);
            op0 = __builtin_amdgcn_mfma_f32_16x16x16bf16_1k(vf[cur][kt*2+0].s4, pp.s4, op0, 0, 0, 0);
            op1 = __builtin_amdgcn_mfma_f32_16x16x16bf16_1k(vf[cur][kt*2+1].s4, pp.s4, op1, 0, 0, 0);
        }
    }

    // per-half row sums (reduce across l4 groups)
    ls += __shfl_xor(ls, 16, 64); ls += __shfl_xor(ls, 32, 64);
    lp += __shfl_xor(lp, 16, 64); lp += __shfl_xor(lp, 32, 64);

    if (kh == 1) {  // upper half: publish partials
#pragma unroll
        for (int r = 0; r < 4; r++) {
            cmb[qt][0][l4 * 4 + r][l15]      = os0[r];
            cmb[qt][0][16 + l4 * 4 + r][l15] = os1[r];
            cmb[qt][1][l4 * 4 + r][l15]      = op0[r];
            cmb[qt][1][16 + l4 * 4 + r][l15] = op1[r];
        }
        if (l4 == 0) { cls[qt][0][l15] = ls; cls[qt][1][l15] = lp; }
    }
    __syncthreads();
    if (kh == 0) {  // lower half: merge + store
        ls += cls[qt][0][l15]; lp += cls[qt][1][l15];
        const float cs = (1.0f - g) / ls;
        const float cp = g / lp;
        const size_t orow = ((size_t)b * NP + myq) * DIM + h * DH;
        U8B o0, o1;
#pragma unroll
        for (int r = 0; r < 4; r++) {
            o0.h[r] = __float2bfloat16(cs * (os0[r] + cmb[qt][0][l4 * 4 + r][l15]) +
                                       cp * (op0[r] + cmb[qt][1][l4 * 4 + r][l15]));
            o1.h[r] = __float2bfloat16(cs * (os1[r] + cmb[qt][0][16 + l4 * 4 + r][l15]) +
                                       cp * (op1[r] + cmb[qt][1][16 + l4 * 4 + r][l15]));
        }
        *(uint2*)(ao + orow + l4 * 4)      = o0.u;
        *(uint2*)(ao + orow + 16 + l4 * 4) = o1.u;
    }
}

// ============ kernel 3: output projection, bf16 MFMA GEMM + bias ============
__global__ __launch_bounds__(256) void proj_mfma(
    const __hip_bfloat16* __restrict__ ao,
    const __hip_bfloat16* __restrict__ WT,   // rows 768..1023
    const float* __restrict__ bias,
    float* __restrict__ out) {
    const int t = threadIdx.x, lane = t & 63, wvid = t >> 6;
    const int l15 = lane & 15, l4 = lane >> 4;
    const int m0 = blockIdx.x * 64;
    const int nc = blockIdx.y * 64 + wvid * 16 + l15;

    f32x4 acc[4] = {{0.f,0.f,0.f,0.f},{0.f,0.f,0.f,0.f},{0.f,0.f,0.f,0.f},{0.f,0.f,0.f,0.f}};
    const __hip_bfloat16* brow = WT + (size_t)(768 + nc) * 256 + l4 * 8;
    const __hip_bfloat16* arow = ao + (size_t)(m0 + l15) * 256 + l4 * 8;

#pragma unroll
    for (int k0 = 0; k0 < 256; k0 += 32) {
        U16B bw; bw.u = *(const uint4*)(brow + k0);
#pragma unroll
        for (int mt = 0; mt < 4; mt++) {
            U16B ax; ax.u = *(const uint4*)(arow + (size_t)mt * 16 * 256 + k0);
            acc[mt] = __builtin_amdgcn_mfma_f32_16x16x32_bf16(ax.s8, bw.s8, acc[mt], 0, 0, 0);
        }
    }

    const float bb = bias[nc];
#pragma unroll
    for (int mt = 0; mt < 4; mt++)
#pragma unroll
        for (int r = 0; r < 4; r++) {
            int tok = m0 + mt * 16 + l4 * 4 + r;
            out[(size_t)tok * 256 + nc] = acc[mt][r] + bb;
        }
}

extern "C" void kernel_launch(void* const* d_in, const int* in_sizes, int n_in,
                              void* d_out, int out_size, void* d_ws, size_t ws_size,
                              hipStream_t stream) {
    const float* x      = (const float*)d_in[0];
    const float* Wqk    = (const float*)d_in[1];
    const float* Wv     = (const float*)d_in[2];
    const float* Wproj  = (const float*)d_in[3];
    const float* bproj  = (const float*)d_in[4];
    const float* Wpos   = (const float*)d_in[5];
    const float* bpos   = (const float*)d_in[6];
    const float* gating = (const float*)d_in[7];
    float* out = (float*)d_out;

    const size_t nElem = (size_t)BATCH * NP * DIM;  // 1,048,576
    char* w = (char*)d_ws;
    __hip_bfloat16* xb = (__hip_bfloat16*)w;        // 2MB; dead after qkv
    __hip_bfloat16* ao = xb;                        // reuses xb
    __hip_bfloat16* WT = xb + nElem;                // 512KB
    __hip_bfloat16* q  = WT + 262144;
    __hip_bfloat16* k  = q + nElem;
    __hip_bfloat16* vT = k + nElem;                 // total ~8.5MB

    prep_kernel<<<576, 256, 0, stream>>>(x, Wqk, Wv, Wproj, WT, xb);
    qkv_mfma<<<dim3(64, 12), 256, 0, stream>>>(xb, WT, q, k, vT);
    attn_kernel<<<BATCH * NH * (NP / 64), 512, 0, stream>>>(q, k, vT, Wpos, bpos, gating, ao);
    proj_mfma<<<dim3(64, 4), 256, 0, stream>>>(ao, WT, bproj, out);
}

// Round 7
// 119.620 us; speedup vs baseline: 1.4354x; 1.4354x over previous
//
#include <hip/hip_runtime.h>
#include <hip/hip_bf16.h>

#define DIM 256
#define NP 2048
#define NH 8
#define BATCH 2
#define DH 32

typedef __attribute__((ext_vector_type(8))) short bshort8;
typedef __attribute__((ext_vector_type(4))) short bshort4;
typedef __attribute__((ext_vector_type(4))) float f32x4;

#define LOG2E 1.44269504f
// (Dh^-0.5) * log2(e), folded into WT rows 0..255 (W_q) at prep time
#define QSCALE (0.17677669529663687f * LOG2E)

union U16B { uint4 u; bshort8 s8; __hip_bfloat16 h[8]; };
union U8B  { uint2 u; bshort4 s4; __hip_bfloat16 h[4]; };

__device__ __forceinline__ float fexp2(float x) { return __builtin_amdgcn_exp2f(x); }
// pack two fp32 -> two bf16 (truncation) in one v_perm
__device__ __forceinline__ unsigned packbf(float hi, float lo) {
    return __builtin_amdgcn_perm(__float_as_uint(hi), __float_as_uint(lo), 0x07060302u);
}

// ============ kernel 0: prep — W transpose->bf16 WT[1024][256], x->bf16 =====
// WT rows: 0-255 = Wq^T * QSCALE, 256-511 = Wk^T, 512-767 = Wv^T, 768-1023 = Wproj^T
__global__ __launch_bounds__(256) void prep_kernel(
    const float* __restrict__ x,
    const float* __restrict__ Wqk,
    const float* __restrict__ Wv,
    const float* __restrict__ Wproj,
    __hip_bfloat16* __restrict__ WT,
    __hip_bfloat16* __restrict__ xb) {
    const int t = threadIdx.x;
    const int blk = blockIdx.x;
    if (blk < 64) {
        __shared__ float ts[64][65];
        const int ct = blk >> 2, k0 = (blk & 3) * 64;
        const int c0 = ct * 64;
        const float* src; int ldw, cs0; float scl = 1.0f;
        if (ct < 8)       { src = Wqk;   ldw = 512; cs0 = c0;      if (ct < 4) scl = QSCALE; }
        else if (ct < 12) { src = Wv;    ldw = 256; cs0 = c0 - 512; }
        else              { src = Wproj; ldw = 256; cs0 = c0 - 768; }
        const int cc = t & 63, tq = t >> 6;
#pragma unroll
        for (int j = 0; j < 16; j++) {
            int kk = tq * 16 + j;
            ts[kk][cc] = src[(size_t)(k0 + kk) * ldw + cs0 + cc];
        }
        __syncthreads();
        const int kk2 = t & 63;
#pragma unroll
        for (int j = 0; j < 16; j++) {
            int cc2 = tq * 16 + j;
            WT[(size_t)(c0 + cc2) * 256 + k0 + kk2] = __float2bfloat16(ts[kk2][cc2] * scl);
        }
    } else {
        const size_t i0 = (size_t)(blk - 64) * 2048 + (size_t)t * 8;
        float4 f0 = *(const float4*)(x + i0);
        float4 f1 = *(const float4*)(x + i0 + 4);
        U16B o;
        o.h[0] = __float2bfloat16(f0.x); o.h[1] = __float2bfloat16(f0.y);
        o.h[2] = __float2bfloat16(f0.z); o.h[3] = __float2bfloat16(f0.w);
        o.h[4] = __float2bfloat16(f1.x); o.h[5] = __float2bfloat16(f1.y);
        o.h[6] = __float2bfloat16(f1.z); o.h[7] = __float2bfloat16(f1.w);
        *(uint4*)(xb + i0) = o.u;
    }
}

// ============ kernel 1: QKV projection, pure bf16 MFMA GEMM =================
__global__ __launch_bounds__(256) void qkv_mfma(
    const __hip_bfloat16* __restrict__ xb,
    const __hip_bfloat16* __restrict__ WT,
    __hip_bfloat16* __restrict__ q,
    __hip_bfloat16* __restrict__ k,
    __hip_bfloat16* __restrict__ vT) {
    const int t = threadIdx.x, lane = t & 63, wvid = t >> 6;
    const int l15 = lane & 15, l4 = lane >> 4;
    const int m0 = blockIdx.x * 64;
    const int nbase = blockIdx.y * 64 + wvid * 16;
    const int nc = nbase + l15;

    f32x4 acc[4] = {{0.f,0.f,0.f,0.f},{0.f,0.f,0.f,0.f},{0.f,0.f,0.f,0.f},{0.f,0.f,0.f,0.f}};
    const __hip_bfloat16* brow = WT + (size_t)nc * 256 + l4 * 8;
    const __hip_bfloat16* arow = xb + (size_t)(m0 + l15) * 256 + l4 * 8;

#pragma unroll
    for (int k0 = 0; k0 < 256; k0 += 32) {
        U16B bw; bw.u = *(const uint4*)(brow + k0);
#pragma unroll
        for (int mt = 0; mt < 4; mt++) {
            U16B ax; ax.u = *(const uint4*)(arow + (size_t)mt * 16 * 256 + k0);
            acc[mt] = __builtin_amdgcn_mfma_f32_16x16x32_bf16(ax.s8, bw.s8, acc[mt], 0, 0, 0);
        }
    }

    if (nbase < 256) {           // q (QSCALE folded into WT)
        const int h = nc >> 5, d = nc & 31;
#pragma unroll
        for (int mt = 0; mt < 4; mt++)
#pragma unroll
            for (int r = 0; r < 4; r++) {
                int tok = m0 + mt * 16 + l4 * 4 + r;
                int b = tok >> 11, n = tok & (NP - 1);
                q[((size_t)(b * NH + h) * NP + n) * DH + d] = __float2bfloat16(acc[mt][r]);
            }
    } else if (nbase < 512) {    // k
        const int c = nc - 256, h = c >> 5, d = c & 31;
#pragma unroll
        for (int mt = 0; mt < 4; mt++)
#pragma unroll
            for (int r = 0; r < 4; r++) {
                int tok = m0 + mt * 16 + l4 * 4 + r;
                int b = tok >> 11, n = tok & (NP - 1);
                k[((size_t)(b * NH + h) * NP + n) * DH + d] = __float2bfloat16(acc[mt][r]);
            }
    } else {                     // vT[(b*256+c)][token], 8B stores
        const int c = nc - 512;
        const int b = m0 >> 11;
#pragma unroll
        for (int mt = 0; mt < 4; mt++) {
            int tokn = (m0 & (NP - 1)) + mt * 16 + l4 * 4;
            U8B vv;
#pragma unroll
            for (int r = 0; r < 4; r++) vv.h[r] = __float2bfloat16(acc[mt][r]);
            *(uint2*)(vT + (size_t)(b * 256 + c) * NP + tokn) = vv.u;
        }
    }
}

// ============ kernel 2: attention — LDS-staged K/V, register P, split-K =====
// grid 512 = bh(16) x qb(32 of 64q). 512 thr / 8 waves: qt = wv&3, kh = wv>>2.
// Wave: 16 queries x 1024 keys (16 iters of 64). Coalesced cooperative staging.
__global__ __launch_bounds__(512, 4) void attn_kernel(
    const __hip_bfloat16* __restrict__ qg,
    const __hip_bfloat16* __restrict__ kg,
    const __hip_bfloat16* __restrict__ vTg,
    const float* __restrict__ Wpos,
    const float* __restrict__ bpos,
    const float* __restrict__ gating,
    __hip_bfloat16* __restrict__ ao) {
    __shared__ __align__(16) __hip_bfloat16 Kt[2][2][64][40];  // [kh][buf][key][dh pad40]
    __shared__ __align__(16) __hip_bfloat16 Vt[2][2][32][68];  // [kh][buf][d][key pad68]
    __shared__ float cmb[4][2][32][16];   // [qt][type][d][q] upper-half partial O
    __shared__ float cls[4][2][16];       // [qt][type][q]    upper-half partial sums

    const int t = threadIdx.x;
    const int lane = t & 63, wvid = t >> 6;
    const int l15 = lane & 15, l4 = lane >> 4;
    const int qt = wvid & 3, kh = wvid >> 2;
    const int bh = blockIdx.x >> 5, qb = blockIdx.x & 31;
    const int h = bh & (NH - 1), b = bh >> 3;
    const int q0 = qb * 64 + qt * 16;
    const int myq = q0 + l15;

    // staging role (same half as this thread's wave: t>>8 == kh)
    const int st_ = t & 255;
    const int kstart = kh * 1024;
    const __hip_bfloat16* kptr = kg + (size_t)bh * NP * DH + (size_t)(kstart + (st_ >> 2)) * DH + (st_ & 3) * 8;
    const __hip_bfloat16* vptr = vTg + ((size_t)bh * DH + (st_ >> 3)) * NP + kstart + (st_ & 7) * 8;

    // preload tile 0
    uint4 kreg = *(const uint4*)kptr;
    uint4 vreg = *(const uint4*)vptr;
    *(uint4*)&Kt[kh][0][st_ >> 2][(st_ & 3) * 8] = kreg;
    *(uint2*)&Vt[kh][0][st_ >> 3][(st_ & 7) * 8]     = make_uint2(vreg.x, vreg.y);
    *(uint2*)&Vt[kh][0][st_ >> 3][(st_ & 7) * 8 + 4] = make_uint2(vreg.z, vreg.w);

    const float w0 = Wpos[h] * LOG2E;
    const float w1 = Wpos[NH + h] * LOG2E;
    const float g = 1.0f / (1.0f + __expf(-gating[h]));
    const float nf = (float)myq;
    // analytic positional max over FULL key range (same for both kh halves)
    const float pmax = fmaxf(0.f, fmaxf((w0 + w1) * nf, (w1 - w0) * (2047.0f - nf)));
    const float npmax = -pmax;
    const float rA = fexp2(-(w0 + w1));   // step d -> d-1 while d-1 >= 0
    const float rB = fexp2(w1 - w0);      // step d -> d-1 while d <= 0

    // Q as B-frag of 16x16x32: B[k=dh=l4*8+j][n=query=l15]
    U16B qv;
    qv.u = *(const uint4*)(qg + ((size_t)bh * NP + myq) * DH + l4 * 8);

    __syncthreads();

    f32x4 os0 = {0.f,0.f,0.f,0.f}, os1 = {0.f,0.f,0.f,0.f};
    f32x4 op0 = {0.f,0.f,0.f,0.f}, op1 = {0.f,0.f,0.f,0.f};
    float ls = 0.f, lp = 0.f;

    for (int it = 0; it < 16; ++it) {
        const int cur = it & 1, nxt = cur ^ 1;

        // prefetch next tile into registers (coalesced)
        if (it < 15) {
            kreg = *(const uint4*)(kptr + (size_t)(it + 1) * 64 * DH);
            vreg = *(const uint4*)(vptr + (it + 1) * 64);
        }

        // S^T = K@Q^T: A-frag from LDS K-tile -> D[key=l4*4+r][query=l15]
        f32x4 st4[4];
#pragma unroll
        for (int kt = 0; kt < 4; kt++) {
            U16B kf; kf.u = *(const uint4*)&Kt[kh][cur][kt * 16 + l15][l4 * 8];
            st4[kt] = __builtin_amdgcn_mfma_f32_16x16x32_bf16(
                kf.s8, qv.s8, (f32x4){0.f,0.f,0.f,0.f}, 0, 0, 0);
        }

        // V^T A-frags (16x16x16): A[m=d=vh*16+l15][k=key=kt*16+l4*4+j]
        U8B vfr[8];
#pragma unroll
        for (int vh = 0; vh < 2; vh++)
#pragma unroll
            for (int kt = 0; kt < 4; kt++)
                vfr[vh * 4 + kt].u = *(const uint2*)&Vt[kh][cur][vh * 16 + l15][kt * 16 + l4 * 4];

        // exp -> pack in registers -> AV MFMAs
        const int kb0 = kstart + it * 64;
#pragma unroll
        for (int kt = 0; kt < 4; kt++) {
            float es0 = fexp2(st4[kt][0]), es1 = fexp2(st4[kt][1]);
            float es2 = fexp2(st4[kt][2]), es3 = fexp2(st4[kt][3]);
            ls += (es0 + es1) + (es2 + es3);
            const float d0 = nf - (float)(kb0 + kt * 16 + l4 * 4);
            float ep0 = fexp2(fmaf(w1, fabsf(d0), fmaf(w0, d0, npmax)));
            float ep1 = ep0 * ((d0 >= 1.f) ? rA : rB);
            float ep2 = ep1 * ((d0 >= 2.f) ? rA : rB);
            float ep3 = ep2 * ((d0 >= 3.f) ? rA : rB);
            lp += (ep0 + ep1) + (ep2 + ep3);
            U8B pc, pp;
            pc.u.x = packbf(es1, es0); pc.u.y = packbf(es3, es2);
            pp.u.x = packbf(ep1, ep0); pp.u.y = packbf(ep3, ep2);
            os0 = __builtin_amdgcn_mfma_f32_16x16x16bf16_1k(vfr[kt].s4,     pc.s4, os0, 0, 0, 0);
            os1 = __builtin_amdgcn_mfma_f32_16x16x16bf16_1k(vfr[4 + kt].s4, pc.s4, os1, 0, 0, 0);
            op0 = __builtin_amdgcn_mfma_f32_16x16x16bf16_1k(vfr[kt].s4,     pp.s4, op0, 0, 0, 0);
            op1 = __builtin_amdgcn_mfma_f32_16x16x16bf16_1k(vfr[4 + kt].s4, pp.s4, op1, 0, 0, 0);
        }

        // stage next tile to LDS
        if (it < 15) {
            *(uint4*)&Kt[kh][nxt][st_ >> 2][(st_ & 3) * 8] = kreg;
            *(uint2*)&Vt[kh][nxt][st_ >> 3][(st_ & 7) * 8]     = make_uint2(vreg.x, vreg.y);
            *(uint2*)&Vt[kh][nxt][st_ >> 3][(st_ & 7) * 8 + 4] = make_uint2(vreg.z, vreg.w);
        }
        __syncthreads();
    }

    // per-half row sums (reduce across l4 groups)
    ls += __shfl_xor(ls, 16, 64); ls += __shfl_xor(ls, 32, 64);
    lp += __shfl_xor(lp, 16, 64); lp += __shfl_xor(lp, 32, 64);

    if (kh == 1) {  // upper half: publish partials
#pragma unroll
        for (int r = 0; r < 4; r++) {
            cmb[qt][0][l4 * 4 + r][l15]      = os0[r];
            cmb[qt][0][16 + l4 * 4 + r][l15] = os1[r];
            cmb[qt][1][l4 * 4 + r][l15]      = op0[r];
            cmb[qt][1][16 + l4 * 4 + r][l15] = op1[r];
        }
        if (l4 == 0) { cls[qt][0][l15] = ls; cls[qt][1][l15] = lp; }
    }
    __syncthreads();
    if (kh == 0) {  // lower half: merge + store
        ls += cls[qt][0][l15]; lp += cls[qt][1][l15];
        const float cs = (1.0f - g) / ls;
        const float cp = g / lp;
        const size_t orow = ((size_t)b * NP + myq) * DIM + h * DH;
        U8B o0, o1;
#pragma unroll
        for (int r = 0; r < 4; r++) {
            o0.h[r] = __float2bfloat16(cs * (os0[r] + cmb[qt][0][l4 * 4 + r][l15]) +
                                       cp * (op0[r] + cmb[qt][1][l4 * 4 + r][l15]));
            o1.h[r] = __float2bfloat16(cs * (os1[r] + cmb[qt][0][16 + l4 * 4 + r][l15]) +
                                       cp * (op1[r] + cmb[qt][1][16 + l4 * 4 + r][l15]));
        }
        *(uint2*)(ao + orow + l4 * 4)      = o0.u;
        *(uint2*)(ao + orow + 16 + l4 * 4) = o1.u;
    }
}

// ============ kernel 3: output projection, bf16 MFMA GEMM + bias ============
__global__ __launch_bounds__(256) void proj_mfma(
    const __hip_bfloat16* __restrict__ ao,
    const __hip_bfloat16* __restrict__ WT,   // rows 768..1023
    const float* __restrict__ bias,
    float* __restrict__ out) {
    const int t = threadIdx.x, lane = t & 63, wvid = t >> 6;
    const int l15 = lane & 15, l4 = lane >> 4;
    const int m0 = blockIdx.x * 64;
    const int nc = blockIdx.y * 64 + wvid * 16 + l15;

    f32x4 acc[4] = {{0.f,0.f,0.f,0.f},{0.f,0.f,0.f,0.f},{0.f,0.f,0.f,0.f},{0.f,0.f,0.f,0.f}};
    const __hip_bfloat16* brow = WT + (size_t)(768 + nc) * 256 + l4 * 8;
    const __hip_bfloat16* arow = ao + (size_t)(m0 + l15) * 256 + l4 * 8;

#pragma unroll
    for (int k0 = 0; k0 < 256; k0 += 32) {
        U16B bw; bw.u = *(const uint4*)(brow + k0);
#pragma unroll
        for (int mt = 0; mt < 4; mt++) {
            U16B ax; ax.u = *(const uint4*)(arow + (size_t)mt * 16 * 256 + k0);
            acc[mt] = __builtin_amdgcn_mfma_f32_16x16x32_bf16(ax.s8, bw.s8, acc[mt], 0, 0, 0);
        }
    }

    const float bb = bias[nc];
#pragma unroll
    for (int mt = 0; mt < 4; mt++)
#pragma unroll
        for (int r = 0; r < 4; r++) {
            int tok = m0 + mt * 16 + l4 * 4 + r;
            out[(size_t)tok * 256 + nc] = acc[mt][r] + bb;
        }
}

extern "C" void kernel_launch(void* const* d_in, const int* in_sizes, int n_in,
                              void* d_out, int out_size, void* d_ws, size_t ws_size,
                              hipStream_t stream) {
    const float* x      = (const float*)d_in[0];
    const float* Wqk    = (const float*)d_in[1];
    const float* Wv     = (const float*)d_in[2];
    const float* Wproj  = (const float*)d_in[3];
    const float* bproj  = (const float*)d_in[4];
    const float* Wpos   = (const float*)d_in[5];
    const float* bpos   = (const float*)d_in[6];
    const float* gating = (const float*)d_in[7];
    float* out = (float*)d_out;

    const size_t nElem = (size_t)BATCH * NP * DIM;  // 1,048,576
    char* w = (char*)d_ws;
    __hip_bfloat16* xb = (__hip_bfloat16*)w;        // 2MB; dead after qkv
    __hip_bfloat16* ao = xb;                        // reuses xb
    __hip_bfloat16* WT = xb + nElem;                // 512KB
    __hip_bfloat16* q  = WT + 262144;
    __hip_bfloat16* k  = q + nElem;
    __hip_bfloat16* vT = k + nElem;                 // total ~8.5MB

    prep_kernel<<<576, 256, 0, stream>>>(x, Wqk, Wv, Wproj, WT, xb);
    qkv_mfma<<<dim3(64, 12), 256, 0, stream>>>(xb, WT, q, k, vT);
    attn_kernel<<<BATCH * NH * (NP / 64), 512, 0, stream>>>(q, k, vT, Wpos, bpos, gating, ao);
    proj_mfma<<<dim3(64, 4), 256, 0, stream>>>(ao, WT, bproj, out);
}

// Round 8
// 107.393 us; speedup vs baseline: 1.5989x; 1.1139x over previous
//
#include <hip/hip_runtime.h>
#include <hip/hip_bf16.h>

#define DIM 256
#define NP 2048
#define NH 8
#define BATCH 2
#define DH 32

typedef __attribute__((ext_vector_type(8))) short bshort8;
typedef __attribute__((ext_vector_type(4))) short bshort4;
typedef __attribute__((ext_vector_type(4))) float f32x4;

#define LOG2E 1.44269504f
// (Dh^-0.5) * log2(e), folded into WT rows 0..255 (W_q) at prep time
#define QSCALE (0.17677669529663687f * LOG2E)

union U16B { uint4 u; bshort8 s8; __hip_bfloat16 h[8]; };
union U8B  { uint2 u; bshort4 s4; __hip_bfloat16 h[4]; };

__device__ __forceinline__ float fexp2(float x) { return __builtin_amdgcn_exp2f(x); }
// pack two fp32 -> two bf16 (truncation) in one v_perm
__device__ __forceinline__ unsigned packbf(float hi, float lo) {
    return __builtin_amdgcn_perm(__float_as_uint(hi), __float_as_uint(lo), 0x07060302u);
}

// LDS tile addressing: 64 rows x 256 elems, XOR-swizzled 16B granules.
// colg = col>>3 (col always 8-aligned). Uniform bank-quad spread for both
// staging writes and ds_read_b128 fragment reads.
__device__ __forceinline__ int lds_addr(int row, int colg) {
    return row * 256 + (((colg ^ (row & 7)) & 31) << 3);
}

// ============ kernel 0: prep — W transpose -> bf16 WT[1024][256] ============
// WT rows: 0-255 Wq^T*QSCALE, 256-511 Wk^T, 512-767 Wv^T, 768-1023 Wproj^T
__global__ __launch_bounds__(256) void prep_kernel(
    const float* __restrict__ Wqk,
    const float* __restrict__ Wv,
    const float* __restrict__ Wproj,
    __hip_bfloat16* __restrict__ WT) {
    const int t = threadIdx.x;
    const int blk = blockIdx.x;
    __shared__ float ts[64][65];
    const int ct = blk >> 2, k0 = (blk & 3) * 64;
    const int c0 = ct * 64;
    const float* src; int ldw, cs0; float scl = 1.0f;
    if (ct < 8)       { src = Wqk;   ldw = 512; cs0 = c0;      if (ct < 4) scl = QSCALE; }
    else if (ct < 12) { src = Wv;    ldw = 256; cs0 = c0 - 512; }
    else              { src = Wproj; ldw = 256; cs0 = c0 - 768; }
    const int cc = t & 63, tq = t >> 6;
#pragma unroll
    for (int j = 0; j < 16; j++) {
        int kk = tq * 16 + j;
        ts[kk][cc] = src[(size_t)(k0 + kk) * ldw + cs0 + cc];
    }
    __syncthreads();
    const int kk2 = t & 63;
#pragma unroll
    for (int j = 0; j < 16; j++) {
        int cc2 = tq * 16 + j;
        WT[(size_t)(c0 + cc2) * 256 + k0 + kk2] = __float2bfloat16(ts[kk2][cc2] * scl);
    }
}

// ============ kernel 1: QKV projection — LDS-tiled bf16 MFMA GEMM ===========
// A = x[4096x256] fp32 (converted during staging), B = WT rows 0..767.
// grid (64,12), 256 thr / 4 waves; block tile 64 tokens x 64 cols, full K=256.
__global__ __launch_bounds__(256) void qkv_mfma(
    const float* __restrict__ x,
    const __hip_bfloat16* __restrict__ WT,
    __hip_bfloat16* __restrict__ q,
    __hip_bfloat16* __restrict__ k,
    __hip_bfloat16* __restrict__ vT) {
    __shared__ __align__(16) __hip_bfloat16 As[64 * 256];
    __shared__ __align__(16) __hip_bfloat16 Bs[64 * 256];
    const int t = threadIdx.x, lane = t & 63, wvid = t >> 6;
    const int l15 = lane & 15, l4 = lane >> 4;
    const int m0 = blockIdx.x * 64;
    const int nb0 = blockIdx.y * 64;
    const int nc = nb0 + wvid * 16 + l15;

    // stage A (fp32 -> bf16 RNE) and B (bf16 copy), fully coalesced
#pragma unroll
    for (int j = 0; j < 8; j++) {
        const int flat = j * 2048 + t * 8;
        const int row = flat >> 8, colg = (flat >> 3) & 31;
        float4 f0 = *(const float4*)(x + (size_t)m0 * 256 + flat);
        float4 f1 = *(const float4*)(x + (size_t)m0 * 256 + flat + 4);
        U16B a;
        a.h[0] = __float2bfloat16(f0.x); a.h[1] = __float2bfloat16(f0.y);
        a.h[2] = __float2bfloat16(f0.z); a.h[3] = __float2bfloat16(f0.w);
        a.h[4] = __float2bfloat16(f1.x); a.h[5] = __float2bfloat16(f1.y);
        a.h[6] = __float2bfloat16(f1.z); a.h[7] = __float2bfloat16(f1.w);
        *(uint4*)&As[lds_addr(row, colg)] = a.u;
        *(uint4*)&Bs[lds_addr(row, colg)] = *(const uint4*)(WT + (size_t)nb0 * 256 + flat);
    }
    __syncthreads();

    f32x4 acc[4] = {{0.f,0.f,0.f,0.f},{0.f,0.f,0.f,0.f},{0.f,0.f,0.f,0.f},{0.f,0.f,0.f,0.f}};
#pragma unroll
    for (int kk = 0; kk < 8; kk++) {
        const int colg = kk * 4 + l4;
        U16B bw; bw.u = *(const uint4*)&Bs[lds_addr(wvid * 16 + l15, colg)];
#pragma unroll
        for (int mt = 0; mt < 4; mt++) {
            U16B ax; ax.u = *(const uint4*)&As[lds_addr(mt * 16 + l15, colg)];
            acc[mt] = __builtin_amdgcn_mfma_f32_16x16x32_bf16(ax.s8, bw.s8, acc[mt], 0, 0, 0);
        }
    }

    if (nb0 < 256) {             // q (QSCALE folded into WT)
        const int h = nc >> 5, d = nc & 31;
#pragma unroll
        for (int mt = 0; mt < 4; mt++)
#pragma unroll
            for (int r = 0; r < 4; r++) {
                int tok = m0 + mt * 16 + l4 * 4 + r;
                int b = tok >> 11, n = tok & (NP - 1);
                q[((size_t)(b * NH + h) * NP + n) * DH + d] = __float2bfloat16(acc[mt][r]);
            }
    } else if (nb0 < 512) {      // k
        const int c = nc - 256, h = c >> 5, d = c & 31;
#pragma unroll
        for (int mt = 0; mt < 4; mt++)
#pragma unroll
            for (int r = 0; r < 4; r++) {
                int tok = m0 + mt * 16 + l4 * 4 + r;
                int b = tok >> 11, n = tok & (NP - 1);
                k[((size_t)(b * NH + h) * NP + n) * DH + d] = __float2bfloat16(acc[mt][r]);
            }
    } else {                     // vT[(b*256+c)][token], 8B stores
        const int c = nc - 512;
        const int b = m0 >> 11;
#pragma unroll
        for (int mt = 0; mt < 4; mt++) {
            int tokn = (m0 & (NP - 1)) + mt * 16 + l4 * 4;
            U8B vv;
#pragma unroll
            for (int r = 0; r < 4; r++) vv.h[r] = __float2bfloat16(acc[mt][r]);
            *(uint2*)(vT + (size_t)(b * 256 + c) * NP + tokn) = vv.u;
        }
    }
}

// ============ kernel 2: attention — LDS-staged K/V, register P, split-K =====
// grid 512 = bh(16) x qb(32 of 64q). 512 thr / 8 waves: qt = wv&3, kh = wv>>2.
__global__ __launch_bounds__(512, 4) void attn_kernel(
    const __hip_bfloat16* __restrict__ qg,
    const __hip_bfloat16* __restrict__ kg,
    const __hip_bfloat16* __restrict__ vTg,
    const float* __restrict__ Wpos,
    const float* __restrict__ bpos,
    const float* __restrict__ gating,
    __hip_bfloat16* __restrict__ ao) {
    __shared__ __align__(16) __hip_bfloat16 Kt[2][2][64][40];  // [kh][buf][key][dh pad40]
    __shared__ __align__(16) __hip_bfloat16 Vt[2][2][32][68];  // [kh][buf][d][key pad68]
    __shared__ float cmb[4][2][32][16];   // [qt][type][d][q] upper-half partial O
    __shared__ float cls[4][2][16];       // [qt][type][q]    upper-half partial sums

    const int t = threadIdx.x;
    const int lane = t & 63, wvid = t >> 6;
    const int l15 = lane & 15, l4 = lane >> 4;
    const int qt = wvid & 3, kh = wvid >> 2;
    const int bh = blockIdx.x >> 5, qb = blockIdx.x & 31;
    const int h = bh & (NH - 1), b = bh >> 3;
    const int q0 = qb * 64 + qt * 16;
    const int myq = q0 + l15;

    const int st_ = t & 255;
    const int kstart = kh * 1024;
    const __hip_bfloat16* kptr = kg + (size_t)bh * NP * DH + (size_t)(kstart + (st_ >> 2)) * DH + (st_ & 3) * 8;
    const __hip_bfloat16* vptr = vTg + ((size_t)bh * DH + (st_ >> 3)) * NP + kstart + (st_ & 7) * 8;

    uint4 kreg = *(const uint4*)kptr;
    uint4 vreg = *(const uint4*)vptr;
    *(uint4*)&Kt[kh][0][st_ >> 2][(st_ & 3) * 8] = kreg;
    *(uint2*)&Vt[kh][0][st_ >> 3][(st_ & 7) * 8]     = make_uint2(vreg.x, vreg.y);
    *(uint2*)&Vt[kh][0][st_ >> 3][(st_ & 7) * 8 + 4] = make_uint2(vreg.z, vreg.w);

    const float w0 = Wpos[h] * LOG2E;
    const float w1 = Wpos[NH + h] * LOG2E;
    const float g = 1.0f / (1.0f + __expf(-gating[h]));
    const float nf = (float)myq;
    const float pmax = fmaxf(0.f, fmaxf((w0 + w1) * nf, (w1 - w0) * (2047.0f - nf)));
    const float npmax = -pmax;
    const float rA = fexp2(-(w0 + w1));
    const float rB = fexp2(w1 - w0);

    U16B qv;
    qv.u = *(const uint4*)(qg + ((size_t)bh * NP + myq) * DH + l4 * 8);

    __syncthreads();

    f32x4 os0 = {0.f,0.f,0.f,0.f}, os1 = {0.f,0.f,0.f,0.f};
    f32x4 op0 = {0.f,0.f,0.f,0.f}, op1 = {0.f,0.f,0.f,0.f};
    float ls = 0.f, lp = 0.f;

    for (int it = 0; it < 16; ++it) {
        const int cur = it & 1, nxt = cur ^ 1;

        if (it < 15) {
            kreg = *(const uint4*)(kptr + (size_t)(it + 1) * 64 * DH);
            vreg = *(const uint4*)(vptr + (it + 1) * 64);
        }

        f32x4 st4[4];
#pragma unroll
        for (int kt = 0; kt < 4; kt++) {
            U16B kf; kf.u = *(const uint4*)&Kt[kh][cur][kt * 16 + l15][l4 * 8];
            st4[kt] = __builtin_amdgcn_mfma_f32_16x16x32_bf16(
                kf.s8, qv.s8, (f32x4){0.f,0.f,0.f,0.f}, 0, 0, 0);
        }

        U8B vfr[8];
#pragma unroll
        for (int vh = 0; vh < 2; vh++)
#pragma unroll
            for (int kt = 0; kt < 4; kt++)
                vfr[vh * 4 + kt].u = *(const uint2*)&Vt[kh][cur][vh * 16 + l15][kt * 16 + l4 * 4];

        const int kb0 = kstart + it * 64;
#pragma unroll
        for (int kt = 0; kt < 4; kt++) {
            float es0 = fexp2(st4[kt][0]), es1 = fexp2(st4[kt][1]);
            float es2 = fexp2(st4[kt][2]), es3 = fexp2(st4[kt][3]);
            ls += (es0 + es1) + (es2 + es3);
            const float d0 = nf - (float)(kb0 + kt * 16 + l4 * 4);
            float ep0 = fexp2(fmaf(w1, fabsf(d0), fmaf(w0, d0, npmax)));
            float ep1 = ep0 * ((d0 >= 1.f) ? rA : rB);
            float ep2 = ep1 * ((d0 >= 2.f) ? rA : rB);
            float ep3 = ep2 * ((d0 >= 3.f) ? rA : rB);
            lp += (ep0 + ep1) + (ep2 + ep3);
            U8B pc, pp;
            pc.u.x = packbf(es1, es0); pc.u.y = packbf(es3, es2);
            pp.u.x = packbf(ep1, ep0); pp.u.y = packbf(ep3, ep2);
            os0 = __builtin_amdgcn_mfma_f32_16x16x16bf16_1k(vfr[kt].s4,     pc.s4, os0, 0, 0, 0);
            os1 = __builtin_amdgcn_mfma_f32_16x16x16bf16_1k(vfr[4 + kt].s4, pc.s4, os1, 0, 0, 0);
            op0 = __builtin_amdgcn_mfma_f32_16x16x16bf16_1k(vfr[kt].s4,     pp.s4, op0, 0, 0, 0);
            op1 = __builtin_amdgcn_mfma_f32_16x16x16bf16_1k(vfr[4 + kt].s4, pp.s4, op1, 0, 0, 0);
        }

        if (it < 15) {
            *(uint4*)&Kt[kh][nxt][st_ >> 2][(st_ & 3) * 8] = kreg;
            *(uint2*)&Vt[kh][nxt][st_ >> 3][(st_ & 7) * 8]     = make_uint2(vreg.x, vreg.y);
            *(uint2*)&Vt[kh][nxt][st_ >> 3][(st_ & 7) * 8 + 4] = make_uint2(vreg.z, vreg.w);
        }
        __syncthreads();
    }

    ls += __shfl_xor(ls, 16, 64); ls += __shfl_xor(ls, 32, 64);
    lp += __shfl_xor(lp, 16, 64); lp += __shfl_xor(lp, 32, 64);

    if (kh == 1) {
#pragma unroll
        for (int r = 0; r < 4; r++) {
            cmb[qt][0][l4 * 4 + r][l15]      = os0[r];
            cmb[qt][0][16 + l4 * 4 + r][l15] = os1[r];
            cmb[qt][1][l4 * 4 + r][l15]      = op0[r];
            cmb[qt][1][16 + l4 * 4 + r][l15] = op1[r];
        }
        if (l4 == 0) { cls[qt][0][l15] = ls; cls[qt][1][l15] = lp; }
    }
    __syncthreads();
    if (kh == 0) {
        ls += cls[qt][0][l15]; lp += cls[qt][1][l15];
        const float cs = (1.0f - g) / ls;
        const float cp = g / lp;
        const size_t orow = ((size_t)b * NP + myq) * DIM + h * DH;
        U8B o0, o1;
#pragma unroll
        for (int r = 0; r < 4; r++) {
            o0.h[r] = __float2bfloat16(cs * (os0[r] + cmb[qt][0][l4 * 4 + r][l15]) +
                                       cp * (op0[r] + cmb[qt][1][l4 * 4 + r][l15]));
            o1.h[r] = __float2bfloat16(cs * (os1[r] + cmb[qt][0][16 + l4 * 4 + r][l15]) +
                                       cp * (op1[r] + cmb[qt][1][16 + l4 * 4 + r][l15]));
        }
        *(uint2*)(ao + orow + l4 * 4)      = o0.u;
        *(uint2*)(ao + orow + 16 + l4 * 4) = o1.u;
    }
}

// ============ kernel 3: output projection — LDS-tiled bf16 MFMA GEMM ========
// A = ao[4096x256] bf16, B = WT rows 768..1023, +bias, out fp32. grid (64,4).
__global__ __launch_bounds__(256) void proj_mfma(
    const __hip_bfloat16* __restrict__ ao,
    const __hip_bfloat16* __restrict__ WT,
    const float* __restrict__ bias,
    float* __restrict__ out) {
    __shared__ __align__(16) __hip_bfloat16 As[64 * 256];
    __shared__ __align__(16) __hip_bfloat16 Bs[64 * 256];
    const int t = threadIdx.x, lane = t & 63, wvid = t >> 6;
    const int l15 = lane & 15, l4 = lane >> 4;
    const int m0 = blockIdx.x * 64;
    const int nb0 = blockIdx.y * 64;
    const int nc = nb0 + wvid * 16 + l15;

#pragma unroll
    for (int j = 0; j < 8; j++) {
        const int flat = j * 2048 + t * 8;
        const int row = flat >> 8, colg = (flat >> 3) & 31;
        *(uint4*)&As[lds_addr(row, colg)] = *(const uint4*)(ao + (size_t)m0 * 256 + flat);
        *(uint4*)&Bs[lds_addr(row, colg)] = *(const uint4*)(WT + (size_t)(768 + nb0) * 256 + flat);
    }
    __syncthreads();

    f32x4 acc[4] = {{0.f,0.f,0.f,0.f},{0.f,0.f,0.f,0.f},{0.f,0.f,0.f,0.f},{0.f,0.f,0.f,0.f}};
#pragma unroll
    for (int kk = 0; kk < 8; kk++) {
        const int colg = kk * 4 + l4;
        U16B bw; bw.u = *(const uint4*)&Bs[lds_addr(wvid * 16 + l15, colg)];
#pragma unroll
        for (int mt = 0; mt < 4; mt++) {
            U16B ax; ax.u = *(const uint4*)&As[lds_addr(mt * 16 + l15, colg)];
            acc[mt] = __builtin_amdgcn_mfma_f32_16x16x32_bf16(ax.s8, bw.s8, acc[mt], 0, 0, 0);
        }
    }

    const float bb = bias[nc];
#pragma unroll
    for (int mt = 0; mt < 4; mt++)
#pragma unroll
        for (int r = 0; r < 4; r++) {
            int tok = m0 + mt * 16 + l4 * 4 + r;
            out[(size_t)tok * 256 + nc] = acc[mt][r] + bb;
        }
}

extern "C" void kernel_launch(void* const* d_in, const int* in_sizes, int n_in,
                              void* d_out, int out_size, void* d_ws, size_t ws_size,
                              hipStream_t stream) {
    const float* x      = (const float*)d_in[0];
    const float* Wqk    = (const float*)d_in[1];
    const float* Wv     = (const float*)d_in[2];
    const float* Wproj  = (const float*)d_in[3];
    const float* bproj  = (const float*)d_in[4];
    const float* Wpos   = (const float*)d_in[5];
    const float* bpos   = (const float*)d_in[6];
    const float* gating = (const float*)d_in[7];
    float* out = (float*)d_out;

    const size_t nElem = (size_t)BATCH * NP * DIM;  // 1,048,576
    char* w = (char*)d_ws;
    __hip_bfloat16* WT = (__hip_bfloat16*)w;        // 512KB
    __hip_bfloat16* q  = WT + 262144;
    __hip_bfloat16* k  = q + nElem;
    __hip_bfloat16* vT = k + nElem;
    __hip_bfloat16* ao = vT + nElem;                // total 8.5MB

    prep_kernel<<<64, 256, 0, stream>>>(Wqk, Wv, Wproj, WT);
    qkv_mfma<<<dim3(64, 12), 256, 0, stream>>>(x, WT, q, k, vT);
    attn_kernel<<<BATCH * NH * (NP / 64), 512, 0, stream>>>(q, k, vT, Wpos, bpos, gating, ao);
    proj_mfma<<<dim3(64, 4), 256, 0, stream>>>(ao, WT, bproj, out);
}